// Round 1
// baseline (251.154 us; speedup 1.0000x reference)
//
#include <hip/hip_runtime.h>
#include <stdint.h>
#include <stddef.h>

// Problem constants
#define BN 16
#define CN 128
#define HN 56
#define WN 56
#define HWN 3136            // H*W
#define FN 9                // K*K deformation taps
#define DN 18               // 2*F offset channels
#define ON 512              // OUT
#define KN 1152             // F*C  (GEMM K)
#define MN 50176            // B*H*W (GEMM M)

typedef __bf16 bf16x8 __attribute__((ext_vector_type(8)));
typedef float f32x4 __attribute__((ext_vector_type(4)));

__device__ __forceinline__ unsigned short f2bf(float f) {
  unsigned int u = __builtin_bit_cast(unsigned int, f);
  u += 0x7fffu + ((u >> 16) & 1u);   // round-to-nearest-even
  return (unsigned short)(u >> 16);
}

__device__ __forceinline__ void gload_lds16(const void* g, void* l) {
  __builtin_amdgcn_global_load_lds(
      (const __attribute__((address_space(1))) unsigned int*)g,
      (__attribute__((address_space(3))) unsigned int*)l, 16, 0, 0);
}

// ---------------- Phase 0a: x fp32 [B,C,HW] -> xt bf16 [B,HW,C] ----------------
__global__ void k_transpose(const float* __restrict__ x, unsigned short* __restrict__ xt) {
  __shared__ float tile[32][33];
  const int b = blockIdx.z;
  const int hw0 = blockIdx.x * 32;   // 3136/32 = 98 exact
  const int c0 = blockIdx.y * 32;    // 128/32 = 4 exact
  const int tx = threadIdx.x & 31;
  const int ty = threadIdx.x >> 5;   // 0..7
  const float* xb = x + (size_t)b * CN * HWN;
  unsigned short* xtb = xt + (size_t)b * HWN * CN;
#pragma unroll
  for (int r = 0; r < 4; ++r)
    tile[ty + r * 8][tx] = xb[(size_t)(c0 + ty + r * 8) * HWN + hw0 + tx];
  __syncthreads();
#pragma unroll
  for (int r = 0; r < 4; ++r)
    xtb[(size_t)(hw0 + ty + r * 8) * CN + c0 + tx] = f2bf(tile[tx][ty + r * 8]);
}

// ---------------- Phase 0b: w_conv fp32 -> bf16 ----------------
__global__ void k_wconv(const float4* __restrict__ w, ushort4* __restrict__ wb) {
  const int i = blockIdx.x * 256 + threadIdx.x;  // 512*1152/4 = 147456 exact
  float4 v = w[i];
  ushort4 o;
  o.x = f2bf(v.x); o.y = f2bf(v.y); o.z = f2bf(v.z); o.w = f2bf(v.w);
  wb[i] = o;
}

// ---------------- Phase 1: per-pixel offset conv -> (ix,iy) per tap ------------
__global__ void k_offsets(const unsigned short* __restrict__ xt, const float* __restrict__ w_off,
                          const float* __restrict__ b_off, float2* __restrict__ ixy) {
  __shared__ float lwoff[DN * CN];
  __shared__ float lboff[DN];
  for (int i = threadIdx.x; i < DN * CN; i += 256) lwoff[i] = w_off[i];
  if (threadIdx.x < DN) lboff[threadIdx.x] = b_off[threadIdx.x];
  __syncthreads();

  const int m = blockIdx.x * 256 + threadIdx.x;  // 50176 = 196*256 exact
  const int b = m / HWN;
  const int hw = m - b * HWN;
  const int h = hw / WN;
  const int w = hw - h * WN;
  const unsigned short* xp = xt + (size_t)m * CN;
  float acc[DN];
#pragma unroll
  for (int d = 0; d < DN; ++d) acc[d] = lboff[d];
  for (int c = 0; c < CN; c += 8) {
    bf16x8 xv = *(const bf16x8*)(xp + c);
    float xf[8];
#pragma unroll
    for (int q = 0; q < 8; ++q) xf[q] = (float)xv[q];
#pragma unroll
    for (int d = 0; d < DN; ++d) {
      float4 w0 = *(const float4*)(lwoff + d * CN + c);      // uniform -> broadcast
      float4 w1 = *(const float4*)(lwoff + d * CN + c + 4);
      acc[d] += xf[0] * w0.x + xf[1] * w0.y + xf[2] * w0.z + xf[3] * w0.w
              + xf[4] * w1.x + xf[5] * w1.y + xf[6] * w1.z + xf[7] * w1.w;
    }
  }
  const float scale = 2.0f / 56.0f;
  const float bx = (2.0f * w + 1.0f) / (float)WN - 1.0f;
  const float by = (2.0f * h + 1.0f) / (float)HN - 1.0f;
#pragma unroll
  for (int f = 0; f < FN; ++f) {
    float gx = bx + acc[2 * f] * scale;
    float gy = by + acc[2 * f + 1] * scale;
    float ixv = ((gx + 1.0f) * (float)WN - 1.0f) * 0.5f;
    float iyv = ((gy + 1.0f) * (float)HN - 1.0f) * 0.5f;
    ixy[(size_t)m * FN + f] = make_float2(ixv, iyv);
  }
}

// ---------------- Phase 2: bilinear sample (bf16 in) -> S bf16 [M, K] ----------
__global__ void k_sample(const unsigned short* __restrict__ xt, const float2* __restrict__ ixy,
                         unsigned short* __restrict__ S) {
  const int g = blockIdx.x * 256 + threadIdx.x;  // 50176*9*8 = 14112*256 exact
  const int cc = g & 7;           // 16-channel chunk
  const int mf = g >> 3;          // m*9 + f
  const int m = mf / FN;
  const int f = mf - m * FN;
  const int b = m / HWN;

  const float2 p = ixy[mf];
  const float ix = p.x, iy = p.y;
  const float x0f = floorf(ix), y0f = floorf(iy);
  const float wx1 = ix - x0f, wy1 = iy - y0f;
  const float wx0 = 1.0f - wx1, wy0 = 1.0f - wy1;
  const int x0 = (int)x0f, y0 = (int)y0f;
  const int x1 = x0 + 1, y1 = y0 + 1;
  const bool vx0 = (x0 >= 0) & (x0 < WN), vx1 = (x1 >= 0) & (x1 < WN);
  const bool vy0 = (y0 >= 0) & (y0 < HN), vy1 = (y1 >= 0) & (y1 < HN);
  const float w00 = wy0 * wx0 * ((vy0 & vx0) ? 1.0f : 0.0f);
  const float w01 = wy0 * wx1 * ((vy0 & vx1) ? 1.0f : 0.0f);
  const float w10 = wy1 * wx0 * ((vy1 & vx0) ? 1.0f : 0.0f);
  const float w11 = wy1 * wx1 * ((vy1 & vx1) ? 1.0f : 0.0f);
  const int x0c = min(max(x0, 0), WN - 1), x1c = min(max(x1, 0), WN - 1);
  const int y0c = min(max(y0, 0), HN - 1), y1c = min(max(y1, 0), HN - 1);

  const unsigned short* bp = xt + (size_t)b * HWN * CN + cc * 16;
  const bf16x8* p00 = (const bf16x8*)(bp + (size_t)(y0c * WN + x0c) * CN);
  const bf16x8* p01 = (const bf16x8*)(bp + (size_t)(y0c * WN + x1c) * CN);
  const bf16x8* p10 = (const bf16x8*)(bp + (size_t)(y1c * WN + x0c) * CN);
  const bf16x8* p11 = (const bf16x8*)(bp + (size_t)(y1c * WN + x1c) * CN);
  bf16x8 a0 = p00[0], a1 = p00[1];
  bf16x8 b0 = p01[0], b1 = p01[1];
  bf16x8 c0 = p10[0], c1 = p10[1];
  bf16x8 d0 = p11[0], d1 = p11[1];

  unsigned short ov[16];
#pragma unroll
  for (int q = 0; q < 8; ++q) {
    float lo = w00 * (float)a0[q] + w01 * (float)b0[q] + w10 * (float)c0[q] + w11 * (float)d0[q];
    float hi = w00 * (float)a1[q] + w01 * (float)b1[q] + w10 * (float)c1[q] + w11 * (float)d1[q];
    ov[q] = f2bf(lo);
    ov[q + 8] = f2bf(hi);
  }
  uint4* dst = (uint4*)(S + (size_t)m * KN + f * CN + cc * 16);
  dst[0] = *(const uint4*)(ov);
  dst[1] = *(const uint4*)(ov + 8);
}

// ---------------- Phase 3: GEMM  out[o,m] = sum_k Wb[o,k]*S[m,k] + bias[o] ------
// 256x256 tile, BK=64, 8 waves (2 o x 4 m), 8-phase schedule (T2+T3+T4+T5):
//  - per phase: ds_read one block C-quadrant's frags, stage ONE 128-row half-tile
//    whose last reader phase has passed, counted vmcnt(4) only at phases 4/8
//    (loads never drain in the main loop), raw s_barrier (no compiler vmcnt(0)),
//    setprio(1) around the 16-MFMA cluster.
//  - LDS 128 KiB: A[par][half][128][64] + B likewise, chunk-XOR swizzle
//    (stored chunk = global chunk ^ (row&7)), linear gload_lds dest with
//    pre-swizzled global source.
//  - steady-state stage plan (it computes K-tiles t=2it in buf0, t+1 in buf1):
//    ph1:A1(t+1) ph2:B1(t+1) ph3:A0(t+2) ph4:B0(t+2)+vmcnt4
//    ph5:A1(t+2) ph6:B1(t+2) ph7:A0(t+3) ph8:B0(t+3)+vmcnt4
//    (each target's last read is >=1 phase before its stage; vmcnt(4)+barrier
//     forces everything a buffer needs before its first reader phase)
#define VMCNT4 asm volatile("s_waitcnt vmcnt(4)" ::: "memory")
#define VMCNT0 asm volatile("s_waitcnt vmcnt(0)" ::: "memory")
#define SBAR   asm volatile("s_barrier" ::: "memory")

__global__ __launch_bounds__(512, 2) void k_gemm(const unsigned short* __restrict__ Wb,
                                                 const unsigned short* __restrict__ S,
                                                 const float* __restrict__ bias,
                                                 float* __restrict__ out) {
  __shared__ __align__(128) char smem[131072];
  const int tid = threadIdx.x;
  const int wave = tid >> 6;
  const int lane = tid & 63;
  const int quad = lane >> 4;
  const int r16 = lane & 15;
  const int wm = wave >> 2;          // 0..1 (o)
  const int wn = wave & 3;           // 0..3 (m)

  // XCD-bijective swizzle: 392 blocks, 49/XCD; the 2 o-tiles of one p-tile
  // (consecutive wgid) come from bids g and g+8 -> same XCD -> shared S in L2.
  const int bid = blockIdx.x;
  const int wgid = (bid & 7) * 49 + (bid >> 3);
  const int o0 = (wgid & 1) * 256;
  const int p0 = (wgid >> 1) * 256;

  f32x4 acc[2][2][4][2];
#pragma unroll
  for (int a = 0; a < 2; ++a)
#pragma unroll
    for (int b = 0; b < 2; ++b)
#pragma unroll
      for (int c = 0; c < 4; ++c)
#pragma unroll
        for (int d = 0; d < 2; ++d) acc[a][b][c][d] = (f32x4){0.f, 0.f, 0.f, 0.f};

  // staging: slot s=rr*512+tid -> half-tile row s/8 (rr=0: rows 0..63, rr=1: 64..127),
  // stored chunk s%8 holds global chunk (s%8)^(row&7); LDS dest linear.
  const int row0 = tid >> 3;                       // 0..63 (+64 for rr=1, same low3)
  const int chunk0 = (tid & 7) ^ (row0 & 7);
  const unsigned short* gA0 = Wb + (size_t)(o0 + row0) * KN + chunk0 * 8;
  const unsigned short* gB0 = S + (size_t)(p0 + row0) * KN + chunk0 * 8;

#define STAGE_A(PAR, HALF, KT) do {                                              \
    const unsigned short* g_ = gA0 + (size_t)(HALF) * 128 * KN + (size_t)(KT) * 64; \
    char* d_ = smem + (PAR) * 32768 + (HALF) * 16384 + tid * 16;                 \
    gload_lds16(g_, d_);                                                         \
    gload_lds16(g_ + (size_t)64 * KN, d_ + 8192);                                \
  } while (0)
#define STAGE_B(PAR, HALF, KT) do {                                              \
    const unsigned short* g_ = gB0 + (size_t)(HALF) * 128 * KN + (size_t)(KT) * 64; \
    char* d_ = smem + 65536 + (PAR) * 32768 + (HALF) * 16384 + tid * 16;         \
    gload_lds16(g_, d_);                                                         \
    gload_lds16(g_ + (size_t)64 * KN, d_ + 8192);                                \
  } while (0)

  // reader: frag row r -> r&7 == r16&7; wanted chunk c -> LDS chunk c^(r16&7)
  const int rsw = r16 & 7;
  const int ch0 = (quad ^ rsw) * 16;   // k in [0,32)
  const int ch1 = ch0 ^ 64;            // k in [32,64)
  const int a_row = (wm * 64 + r16) * 128;   // bytes within A half-tile
  const int b_row = (wn * 32 + r16) * 128;   // bytes within B half-tile

#define PHASE(PAR, QI, QJ, STAGE_STMT, WAIT_STMT) do {                           \
    const char* pa_ = smem + (PAR) * 32768 + (QI) * 16384 + a_row;               \
    const char* pb_ = smem + 65536 + (PAR) * 32768 + (QJ) * 16384 + b_row;       \
    bf16x8 a0_ = *(const bf16x8*)(pa_ + 0 * 2048 + ch0);                         \
    bf16x8 a1_ = *(const bf16x8*)(pa_ + 1 * 2048 + ch0);                         \
    bf16x8 a2_ = *(const bf16x8*)(pa_ + 2 * 2048 + ch0);                         \
    bf16x8 a3_ = *(const bf16x8*)(pa_ + 3 * 2048 + ch0);                         \
    bf16x8 b0_ = *(const bf16x8*)(pb_ + 0 * 2048 + ch0);                         \
    bf16x8 b1_ = *(const bf16x8*)(pb_ + 1 * 2048 + ch0);                         \
    bf16x8 a4_ = *(const bf16x8*)(pa_ + 0 * 2048 + ch1);                         \
    bf16x8 a5_ = *(const bf16x8*)(pa_ + 1 * 2048 + ch1);                         \
    bf16x8 a6_ = *(const bf16x8*)(pa_ + 2 * 2048 + ch1);                         \
    bf16x8 a7_ = *(const bf16x8*)(pa_ + 3 * 2048 + ch1);                         \
    bf16x8 b2_ = *(const bf16x8*)(pb_ + 0 * 2048 + ch1);                         \
    bf16x8 b3_ = *(const bf16x8*)(pb_ + 1 * 2048 + ch1);                         \
    STAGE_STMT;                                                                  \
    WAIT_STMT;                                                                   \
    SBAR;                                                                        \
    __builtin_amdgcn_s_setprio(1);                                               \
    acc[QI][QJ][0][0] = __builtin_amdgcn_mfma_f32_16x16x32_bf16(a0_, b0_, acc[QI][QJ][0][0], 0, 0, 0); \
    acc[QI][QJ][0][1] = __builtin_amdgcn_mfma_f32_16x16x32_bf16(a0_, b1_, acc[QI][QJ][0][1], 0, 0, 0); \
    acc[QI][QJ][1][0] = __builtin_amdgcn_mfma_f32_16x16x32_bf16(a1_, b0_, acc[QI][QJ][1][0], 0, 0, 0); \
    acc[QI][QJ][1][1] = __builtin_amdgcn_mfma_f32_16x16x32_bf16(a1_, b1_, acc[QI][QJ][1][1], 0, 0, 0); \
    acc[QI][QJ][2][0] = __builtin_amdgcn_mfma_f32_16x16x32_bf16(a2_, b0_, acc[QI][QJ][2][0], 0, 0, 0); \
    acc[QI][QJ][2][1] = __builtin_amdgcn_mfma_f32_16x16x32_bf16(a2_, b1_, acc[QI][QJ][2][1], 0, 0, 0); \
    acc[QI][QJ][3][0] = __builtin_amdgcn_mfma_f32_16x16x32_bf16(a3_, b0_, acc[QI][QJ][3][0], 0, 0, 0); \
    acc[QI][QJ][3][1] = __builtin_amdgcn_mfma_f32_16x16x32_bf16(a3_, b1_, acc[QI][QJ][3][1], 0, 0, 0); \
    acc[QI][QJ][0][0] = __builtin_amdgcn_mfma_f32_16x16x32_bf16(a4_, b2_, acc[QI][QJ][0][0], 0, 0, 0); \
    acc[QI][QJ][0][1] = __builtin_amdgcn_mfma_f32_16x16x32_bf16(a4_, b3_, acc[QI][QJ][0][1], 0, 0, 0); \
    acc[QI][QJ][1][0] = __builtin_amdgcn_mfma_f32_16x16x32_bf16(a5_, b2_, acc[QI][QJ][1][0], 0, 0, 0); \
    acc[QI][QJ][1][1] = __builtin_amdgcn_mfma_f32_16x16x32_bf16(a5_, b3_, acc[QI][QJ][1][1], 0, 0, 0); \
    acc[QI][QJ][2][0] = __builtin_amdgcn_mfma_f32_16x16x32_bf16(a6_, b2_, acc[QI][QJ][2][0], 0, 0, 0); \
    acc[QI][QJ][2][1] = __builtin_amdgcn_mfma_f32_16x16x32_bf16(a6_, b3_, acc[QI][QJ][2][1], 0, 0, 0); \
    acc[QI][QJ][3][0] = __builtin_amdgcn_mfma_f32_16x16x32_bf16(a7_, b2_, acc[QI][QJ][3][0], 0, 0, 0); \
    acc[QI][QJ][3][1] = __builtin_amdgcn_mfma_f32_16x16x32_bf16(a7_, b3_, acc[QI][QJ][3][1], 0, 0, 0); \
    __builtin_amdgcn_s_setprio(0);                                               \
    SBAR;                                                                        \
  } while (0)

  // Prologue: K-tile 0 -> buf0 (4 half-tiles), A0/B0 of K-tile 1 -> buf1.
  // vmcnt(4): buf0 fully landed, buf1.A0/B0 still in flight.
  STAGE_A(0, 0, 0); STAGE_B(0, 0, 0); STAGE_A(0, 1, 0); STAGE_B(0, 1, 0);
  STAGE_A(1, 0, 1); STAGE_B(1, 0, 1);
  VMCNT4;
  SBAR;

#pragma unroll 1
  for (int it = 0; it < 8; ++it) {
    const int t1 = 2 * it + 1, t2 = 2 * it + 2, t3 = 2 * it + 3;
    PHASE(0, 0, 0, STAGE_A(1, 1, t1), (void)0);
    PHASE(0, 0, 1, STAGE_B(1, 1, t1), (void)0);
    PHASE(0, 1, 0, STAGE_A(0, 0, t2), (void)0);
    PHASE(0, 1, 1, STAGE_B(0, 0, t2), VMCNT4);
    PHASE(1, 0, 0, STAGE_A(0, 1, t2), (void)0);
    PHASE(1, 0, 1, STAGE_B(0, 1, t2), (void)0);
    PHASE(1, 1, 0, STAGE_A(1, 0, t3), (void)0);
    PHASE(1, 1, 1, STAGE_B(1, 0, t3), VMCNT4);
  }
  // Peeled last iteration (K-tiles 16/17): only buf1.A1/B1(17) left to stage;
  // drain with vmcnt(0) at phase 4 (no loads remain afterwards).
  PHASE(0, 0, 0, STAGE_A(1, 1, 17), (void)0);
  PHASE(0, 0, 1, STAGE_B(1, 1, 17), (void)0);
  PHASE(0, 1, 0, (void)0, (void)0);
  PHASE(0, 1, 1, (void)0, VMCNT0);
  PHASE(1, 0, 0, (void)0, (void)0);
  PHASE(1, 0, 1, (void)0, (void)0);
  PHASE(1, 1, 0, (void)0, (void)0);
  PHASE(1, 1, 1, (void)0, (void)0);

  // Epilogue: 8 rounds of 32 o-rows x 256 m staged fp32 in LDS (stride 260
  // breaks the quad-row bank alias), then full float4 lines to global.
  // C/D layout: col(m)=r16, row(o)=quad*4+reg.
  float* lout = (float*)smem;
  const int LSTR = 260;
#pragma unroll
  for (int ob = 0; ob < 8; ++ob) {
    const int Qi = ob >> 2, wsel = (ob >> 1) & 1, s2 = ob & 1;
    __syncthreads();
    if (wm == wsel) {
#pragma unroll
      for (int il = 0; il < 2; ++il) {
        const int i = s2 * 2 + il;
#pragma unroll
        for (int Qj = 0; Qj < 2; ++Qj)
#pragma unroll
          for (int j = 0; j < 2; ++j) {
            f32x4 v = acc[Qi][Qj][i][j];
            const int col = Qj * 128 + wn * 32 + j * 16 + r16;
            const int rb = il * 16 + quad * 4;
            lout[(rb + 0) * LSTR + col] = v[0];
            lout[(rb + 1) * LSTR + col] = v[1];
            lout[(rb + 2) * LSTR + col] = v[2];
            lout[(rb + 3) * LSTR + col] = v[3];
          }
      }
    }
    __syncthreads();
#pragma unroll
    for (int tl = 0; tl < 4; ++tl) {
      const int idx = tl * 512 + tid;         // 2048 f4 = 32 rows x 64 f4
      const int rr = idx >> 6, c4 = idx & 63;
      float4 v = *(const float4*)(lout + rr * LSTR + c4 * 4);
      const int o = o0 + ob * 32 + rr;
      const float bv = bias[o];
      v.x += bv; v.y += bv; v.z += bv; v.w += bv;
      const int p = p0 + c4 * 4;
      const int bidx = p / HWN;               // 3136 % 4 == 0 -> no b straddle
      const int hw = p - bidx * HWN;
      *(float4*)(out + (size_t)bidx * ON * HWN + (size_t)o * HWN + hw) = v;
    }
  }
#undef PHASE
#undef STAGE_A
#undef STAGE_B
}

extern "C" void kernel_launch(void* const* d_in, const int* in_sizes, int n_in,
                              void* d_out, int out_size, void* d_ws, size_t ws_size,
                              hipStream_t stream) {
  const float* x = (const float*)d_in[0];       // [16,128,56,56]
  const float* w_off = (const float*)d_in[1];   // [18,128]
  const float* b_off = (const float*)d_in[2];   // [18]
  const float* w_conv = (const float*)d_in[3];  // [512,1152]
  const float* b_conv = (const float*)d_in[4];  // [512]
  float* out = (float*)d_out;                   // [16,512,56,56] fp32

  // workspace layout (16B aligned):
  //   xt  : bf16 [B,HW,C]      12,845,056 B @ 0
  //   S   : bf16 [M,K]        115,605,504 B @ 12,845,056
  //   Wb  : bf16 [512,1152]     1,179,648 B @ 128,450,560
  //   ixy : float2 [M,F]        3,612,672 B @ 129,630,208   (total ~133.2 MB)
  char* ws = (char*)d_ws;
  unsigned short* xt = (unsigned short*)(ws);
  unsigned short* S = (unsigned short*)(ws + 12845056);
  unsigned short* Wb = (unsigned short*)(ws + 128450560);
  float2* ixy = (float2*)(ws + 129630208);

  k_transpose<<<dim3(98, 4, 16), 256, 0, stream>>>(x, xt);
  k_wconv<<<dim3(576), 256, 0, stream>>>((const float4*)w_conv, (ushort4*)Wb);
  k_offsets<<<dim3(196), 256, 0, stream>>>(xt, w_off, b_off, ixy);
  k_sample<<<dim3(14112), 256, 0, stream>>>(xt, ixy, S);
  k_gemm<<<dim3(392), 512, 0, stream>>>(Wb, S, b_conv, out);
}

// Round 2
// 248.531 us; speedup vs baseline: 1.0106x; 1.0106x over previous
//
#include <hip/hip_runtime.h>
#include <stdint.h>
#include <stddef.h>

// Problem constants
#define BN 16
#define CN 128
#define HN 56
#define WN 56
#define HWN 3136            // H*W
#define FN 9                // K*K deformation taps
#define DN 18               // 2*F offset channels
#define ON 512              // OUT
#define KN 1152             // F*C  (GEMM K)
#define MN 50176            // B*H*W (GEMM M)

typedef __bf16 bf16x8 __attribute__((ext_vector_type(8)));
typedef float f32x4 __attribute__((ext_vector_type(4)));

__device__ __forceinline__ unsigned short f2bf(float f) {
  unsigned int u = __builtin_bit_cast(unsigned int, f);
  u += 0x7fffu + ((u >> 16) & 1u);   // round-to-nearest-even
  return (unsigned short)(u >> 16);
}

__device__ __forceinline__ void gload_lds16(const void* g, void* l) {
  __builtin_amdgcn_global_load_lds(
      (const __attribute__((address_space(1))) unsigned int*)g,
      (__attribute__((address_space(3))) unsigned int*)l, 16, 0, 0);
}

// ---------------- Phase 0a: x fp32 [B,C,HW] -> xt bf16 [B,HW,C] ----------------
__global__ void k_transpose(const float* __restrict__ x, unsigned short* __restrict__ xt) {
  __shared__ float tile[32][33];
  const int b = blockIdx.z;
  const int hw0 = blockIdx.x * 32;   // 3136/32 = 98 exact
  const int c0 = blockIdx.y * 32;    // 128/32 = 4 exact
  const int tx = threadIdx.x & 31;
  const int ty = threadIdx.x >> 5;   // 0..7
  const float* xb = x + (size_t)b * CN * HWN;
  unsigned short* xtb = xt + (size_t)b * HWN * CN;
#pragma unroll
  for (int r = 0; r < 4; ++r)
    tile[ty + r * 8][tx] = xb[(size_t)(c0 + ty + r * 8) * HWN + hw0 + tx];
  __syncthreads();
#pragma unroll
  for (int r = 0; r < 4; ++r)
    xtb[(size_t)(hw0 + ty + r * 8) * CN + c0 + tx] = f2bf(tile[tx][ty + r * 8]);
}

// ---------------- Phase 0b: w_conv fp32 -> bf16 ----------------
__global__ void k_wconv(const float4* __restrict__ w, ushort4* __restrict__ wb) {
  const int i = blockIdx.x * 256 + threadIdx.x;  // 512*1152/4 = 147456 exact
  float4 v = w[i];
  ushort4 o;
  o.x = f2bf(v.x); o.y = f2bf(v.y); o.z = f2bf(v.z); o.w = f2bf(v.w);
  wb[i] = o;
}

// ---------------- Phase 1: per-pixel offset conv -> (ix,iy) per tap ------------
__global__ void k_offsets(const unsigned short* __restrict__ xt, const float* __restrict__ w_off,
                          const float* __restrict__ b_off, float2* __restrict__ ixy) {
  __shared__ float lwoff[DN * CN];
  __shared__ float lboff[DN];
  for (int i = threadIdx.x; i < DN * CN; i += 256) lwoff[i] = w_off[i];
  if (threadIdx.x < DN) lboff[threadIdx.x] = b_off[threadIdx.x];
  __syncthreads();

  const int m = blockIdx.x * 256 + threadIdx.x;  // 50176 = 196*256 exact
  const int b = m / HWN;
  const int hw = m - b * HWN;
  const int h = hw / WN;
  const int w = hw - h * WN;
  const unsigned short* xp = xt + (size_t)m * CN;
  float acc[DN];
#pragma unroll
  for (int d = 0; d < DN; ++d) acc[d] = lboff[d];
  for (int c = 0; c < CN; c += 8) {
    bf16x8 xv = *(const bf16x8*)(xp + c);
    float xf[8];
#pragma unroll
    for (int q = 0; q < 8; ++q) xf[q] = (float)xv[q];
#pragma unroll
    for (int d = 0; d < DN; ++d) {
      float4 w0 = *(const float4*)(lwoff + d * CN + c);      // uniform -> broadcast
      float4 w1 = *(const float4*)(lwoff + d * CN + c + 4);
      acc[d] += xf[0] * w0.x + xf[1] * w0.y + xf[2] * w0.z + xf[3] * w0.w
              + xf[4] * w1.x + xf[5] * w1.y + xf[6] * w1.z + xf[7] * w1.w;
    }
  }
  const float scale = 2.0f / 56.0f;
  const float bx = (2.0f * w + 1.0f) / (float)WN - 1.0f;
  const float by = (2.0f * h + 1.0f) / (float)HN - 1.0f;
#pragma unroll
  for (int f = 0; f < FN; ++f) {
    float gx = bx + acc[2 * f] * scale;
    float gy = by + acc[2 * f + 1] * scale;
    float ixv = ((gx + 1.0f) * (float)WN - 1.0f) * 0.5f;
    float iyv = ((gy + 1.0f) * (float)HN - 1.0f) * 0.5f;
    ixy[(size_t)m * FN + f] = make_float2(ixv, iyv);
  }
}

// ---------------- Phase 2: bilinear sample (bf16 in) -> S bf16 [M, K] ----------
__global__ void k_sample(const unsigned short* __restrict__ xt, const float2* __restrict__ ixy,
                         unsigned short* __restrict__ S) {
  const int g = blockIdx.x * 256 + threadIdx.x;  // 50176*9*8 = 14112*256 exact
  const int cc = g & 7;           // 16-channel chunk
  const int mf = g >> 3;          // m*9 + f
  const int m = mf / FN;
  const int f = mf - m * FN;
  const int b = m / HWN;

  const float2 p = ixy[mf];
  const float ix = p.x, iy = p.y;
  const float x0f = floorf(ix), y0f = floorf(iy);
  const float wx1 = ix - x0f, wy1 = iy - y0f;
  const float wx0 = 1.0f - wx1, wy0 = 1.0f - wy1;
  const int x0 = (int)x0f, y0 = (int)y0f;
  const int x1 = x0 + 1, y1 = y0 + 1;
  const bool vx0 = (x0 >= 0) & (x0 < WN), vx1 = (x1 >= 0) & (x1 < WN);
  const bool vy0 = (y0 >= 0) & (y0 < HN), vy1 = (y1 >= 0) & (y1 < HN);
  const float w00 = wy0 * wx0 * ((vy0 & vx0) ? 1.0f : 0.0f);
  const float w01 = wy0 * wx1 * ((vy0 & vx1) ? 1.0f : 0.0f);
  const float w10 = wy1 * wx0 * ((vy1 & vx0) ? 1.0f : 0.0f);
  const float w11 = wy1 * wx1 * ((vy1 & vx1) ? 1.0f : 0.0f);
  const int x0c = min(max(x0, 0), WN - 1), x1c = min(max(x1, 0), WN - 1);
  const int y0c = min(max(y0, 0), HN - 1), y1c = min(max(y1, 0), HN - 1);

  const unsigned short* bp = xt + (size_t)b * HWN * CN + cc * 16;
  const bf16x8* p00 = (const bf16x8*)(bp + (size_t)(y0c * WN + x0c) * CN);
  const bf16x8* p01 = (const bf16x8*)(bp + (size_t)(y0c * WN + x1c) * CN);
  const bf16x8* p10 = (const bf16x8*)(bp + (size_t)(y1c * WN + x0c) * CN);
  const bf16x8* p11 = (const bf16x8*)(bp + (size_t)(y1c * WN + x1c) * CN);
  bf16x8 a0 = p00[0], a1 = p00[1];
  bf16x8 b0 = p01[0], b1 = p01[1];
  bf16x8 c0 = p10[0], c1 = p10[1];
  bf16x8 d0 = p11[0], d1 = p11[1];

  unsigned short ov[16];
#pragma unroll
  for (int q = 0; q < 8; ++q) {
    float lo = w00 * (float)a0[q] + w01 * (float)b0[q] + w10 * (float)c0[q] + w11 * (float)d0[q];
    float hi = w00 * (float)a1[q] + w01 * (float)b1[q] + w10 * (float)c1[q] + w11 * (float)d1[q];
    ov[q] = f2bf(lo);
    ov[q + 8] = f2bf(hi);
  }
  uint4* dst = (uint4*)(S + (size_t)m * KN + f * CN + cc * 16);
  dst[0] = *(const uint4*)(ov);
  dst[1] = *(const uint4*)(ov + 8);
}

// ---------------- Phase 3: GEMM  out[o,m] = sum_k Wb[o,k]*S[m,k] + bias[o] ------
// 256x256 tile, BK=64, 8 waves (2 o x 4 m), 8-phase ZIGZAG schedule:
//   quadrant order per buffer: (0,0)->(0,1)->(1,1)->(1,0) with A-frags and BOTH
//   B-frag sets held in registers -> LDS reads/iter per wave 96 -> 48 (the
//   unique minimum). R1 post-mortem: kernel was LDS-read-BW-bound (12 reads x
//   8 waves x 1KiB per phase vs ~155cy of MFMA), not barrier-bound.
// Stage plan (1 half-tile = 2 gload_lds16/thread per phase):
//   P1:A1h1(t1) P2:A0h0(t2) P3:B0h0(t2) P4:B0h1(t2)+vmcnt(6)
//   P5:A0h1(t2) P6:A1h0(t3) P7:B1h0(t3) P8:B1h1(t3)+vmcnt(6)
// Every staged half has >=6 phases before its first reader; WAR all >=1 barrier.
// vmcnt(6): 3 stages (6 loads) stay in flight across every barrier.
#define VMCNT6 asm volatile("s_waitcnt vmcnt(6)" ::: "memory")
#define VMCNT0 asm volatile("s_waitcnt vmcnt(0)" ::: "memory")
#define SBAR   asm volatile("s_barrier" ::: "memory")

__global__ __launch_bounds__(512, 2) void k_gemm(const unsigned short* __restrict__ Wb,
                                                 const unsigned short* __restrict__ S,
                                                 const float* __restrict__ bias,
                                                 float* __restrict__ out) {
  __shared__ __align__(128) char smem[131072];
  const int tid = threadIdx.x;
  const int wave = tid >> 6;
  const int lane = tid & 63;
  const int quad = lane >> 4;
  const int r16 = lane & 15;
  const int wm = wave >> 2;          // 0..1 (o)
  const int wn = wave & 3;           // 0..3 (m)

  // XCD-bijective swizzle: 392 blocks, 49/XCD; the 2 o-tiles of one p-tile
  // land on the SAME XCD -> shared S in L2.
  const int bid = blockIdx.x;
  const int wgid = (bid & 7) * 49 + (bid >> 3);
  const int o0 = (wgid & 1) * 256;
  const int p0 = (wgid >> 1) * 256;

  f32x4 acc[2][2][4][2];
#pragma unroll
  for (int a = 0; a < 2; ++a)
#pragma unroll
    for (int b = 0; b < 2; ++b)
#pragma unroll
      for (int c = 0; c < 4; ++c)
#pragma unroll
        for (int d = 0; d < 2; ++d) acc[a][b][c][d] = (f32x4){0.f, 0.f, 0.f, 0.f};

  // staging: slot s=rr*512+tid -> half-tile row s/8, stored chunk s%8 holds
  // global chunk (s%8)^(row&7); LDS dest linear (gload_lds requirement).
  const int row0 = tid >> 3;                       // 0..63 (+64 for rr=1)
  const int chunk0 = (tid & 7) ^ (row0 & 7);
  const unsigned short* gA0 = Wb + (size_t)(o0 + row0) * KN + chunk0 * 8;
  const unsigned short* gB0 = S + (size_t)(p0 + row0) * KN + chunk0 * 8;

#define STAGE_A(PAR, HALF, KT) do {                                              \
    const unsigned short* g_ = gA0 + (size_t)(HALF) * 128 * KN + (size_t)(KT) * 64; \
    char* d_ = smem + (PAR) * 32768 + (HALF) * 16384 + tid * 16;                 \
    gload_lds16(g_, d_);                                                         \
    gload_lds16(g_ + (size_t)64 * KN, d_ + 8192);                                \
  } while (0)
#define STAGE_B(PAR, HALF, KT) do {                                              \
    const unsigned short* g_ = gB0 + (size_t)(HALF) * 128 * KN + (size_t)(KT) * 64; \
    char* d_ = smem + 65536 + (PAR) * 32768 + (HALF) * 16384 + tid * 16;         \
    gload_lds16(g_, d_);                                                         \
    gload_lds16(g_ + (size_t)64 * KN, d_ + 8192);                                \
  } while (0)

  // reader: frag row r -> r&7 == r16&7; wanted chunk c -> LDS chunk c^(r16&7)
  const int rsw = r16 & 7;
  const int ch0 = (quad ^ rsw) * 16;   // k in [0,32), byte offset
  const int ch1 = ch0 ^ 64;            // k in [32,64)
  const int a_row = (wm * 64 + r16) * 128;   // bytes within A half-tile
  const int b_row = (wn * 32 + r16) * 128;   // bytes within B half-tile

  bf16x8 afr[8], bfr0[4], bfr1[4];

#define LOAD_A(PAR, H) do {                                                      \
    const char* pa_ = smem + (PAR) * 32768 + (H) * 16384 + a_row;                \
    _Pragma("unroll") for (int i_ = 0; i_ < 4; ++i_) {                           \
      afr[i_ * 2 + 0] = *(const bf16x8*)(pa_ + i_ * 2048 + ch0);                 \
      afr[i_ * 2 + 1] = *(const bf16x8*)(pa_ + i_ * 2048 + ch1);                 \
    } } while (0)
#define LOAD_B(PAR, H, DST) do {                                                 \
    const char* pb_ = smem + 65536 + (PAR) * 32768 + (H) * 16384 + b_row;        \
    _Pragma("unroll") for (int j_ = 0; j_ < 2; ++j_) {                           \
      DST[j_ * 2 + 0] = *(const bf16x8*)(pb_ + j_ * 2048 + ch0);                 \
      DST[j_ * 2 + 1] = *(const bf16x8*)(pb_ + j_ * 2048 + ch1);                 \
    } } while (0)
#define MFMA16(QI, QJ, BF) do {                                                  \
    __builtin_amdgcn_s_setprio(1);                                               \
    _Pragma("unroll") for (int i_ = 0; i_ < 4; ++i_)                             \
    _Pragma("unroll") for (int j_ = 0; j_ < 2; ++j_) {                           \
      acc[QI][QJ][i_][j_] = __builtin_amdgcn_mfma_f32_16x16x32_bf16(             \
          afr[i_ * 2 + 0], BF[j_ * 2 + 0], acc[QI][QJ][i_][j_], 0, 0, 0);        \
      acc[QI][QJ][i_][j_] = __builtin_amdgcn_mfma_f32_16x16x32_bf16(             \
          afr[i_ * 2 + 1], BF[j_ * 2 + 1], acc[QI][QJ][i_][j_], 0, 0, 0);        \
    }                                                                            \
    __builtin_amdgcn_s_setprio(0); } while (0)

  // Four phase flavors (zigzag): reads differ, skeleton identical.
#define PH00(PAR, STG, WT) do { LOAD_A(PAR, 0); LOAD_B(PAR, 0, bfr0); STG; WT; SBAR; MFMA16(0, 0, bfr0); SBAR; } while (0)
#define PH01(PAR, STG, WT) do { LOAD_B(PAR, 1, bfr1); STG; WT; SBAR; MFMA16(0, 1, bfr1); SBAR; } while (0)
#define PH11(PAR, STG, WT) do { LOAD_A(PAR, 1); STG; WT; SBAR; MFMA16(1, 1, bfr1); SBAR; } while (0)
#define PH10(PAR, STG, WT) do { STG; WT; SBAR; MFMA16(1, 0, bfr0); SBAR; } while (0)

  // Prologue: buf0 <- tile 0 (4 halves), buf1 <- A1h0/B1h0/B1h1 of tile 1.
  // vmcnt(6): buf0 fully landed; 3 buf1 stages (6 loads) in flight.
  STAGE_A(0, 0, 0); STAGE_B(0, 0, 0); STAGE_B(0, 1, 0); STAGE_A(0, 1, 0);
  STAGE_A(1, 0, 1); STAGE_B(1, 0, 1); STAGE_B(1, 1, 1);
  VMCNT6;
  SBAR;

#pragma unroll 1
  for (int it = 0; it < 8; ++it) {
    const int t1 = 2 * it + 1, t2 = 2 * it + 2, t3 = 2 * it + 3;
    PH00(0, STAGE_A(1, 1, t1), (void)0);
    PH01(0, STAGE_A(0, 0, t2), (void)0);
    PH11(0, STAGE_B(0, 0, t2), (void)0);
    PH10(0, STAGE_B(0, 1, t2), VMCNT6);
    PH00(1, STAGE_A(0, 1, t2), (void)0);
    PH01(1, STAGE_A(1, 0, t3), (void)0);
    PH11(1, STAGE_B(1, 0, t3), (void)0);
    PH10(1, STAGE_B(1, 1, t3), VMCNT6);
  }
  // Peeled last iteration (tiles 16 in buf0, 17 in buf1): only A1h1(17) left
  // to stage (P1); full drain at P4; no loads outstanding afterwards.
  PH00(0, STAGE_A(1, 1, 17), (void)0);
  PH01(0, (void)0, (void)0);
  PH11(0, (void)0, (void)0);
  PH10(0, (void)0, VMCNT0);
  PH00(1, (void)0, (void)0);
  PH01(1, (void)0, (void)0);
  PH11(1, (void)0, (void)0);
  PH10(1, (void)0, (void)0);

  // Epilogue: 8 rounds of 32 o-rows x 256 m staged fp32 in LDS (stride 260
  // breaks the quad-row bank alias), then full float4 lines to global.
  // C/D layout: col(m)=r16, row(o)=quad*4+reg.
  float* lout = (float*)smem;
  const int LSTR = 260;
#pragma unroll
  for (int ob = 0; ob < 8; ++ob) {
    const int Qi = ob >> 2, wsel = (ob >> 1) & 1, s2 = ob & 1;
    __syncthreads();
    if (wm == wsel) {
#pragma unroll
      for (int il = 0; il < 2; ++il) {
        const int i = s2 * 2 + il;
#pragma unroll
        for (int Qj = 0; Qj < 2; ++Qj)
#pragma unroll
          for (int j = 0; j < 2; ++j) {
            f32x4 v = acc[Qi][Qj][i][j];
            const int col = Qj * 128 + wn * 32 + j * 16 + r16;
            const int rb = il * 16 + quad * 4;
            lout[(rb + 0) * LSTR + col] = v[0];
            lout[(rb + 1) * LSTR + col] = v[1];
            lout[(rb + 2) * LSTR + col] = v[2];
            lout[(rb + 3) * LSTR + col] = v[3];
          }
      }
    }
    __syncthreads();
#pragma unroll
    for (int tl = 0; tl < 4; ++tl) {
      const int idx = tl * 512 + tid;         // 2048 f4 = 32 rows x 64 f4
      const int rr = idx >> 6, c4 = idx & 63;
      float4 v = *(const float4*)(lout + rr * LSTR + c4 * 4);
      const int o = o0 + ob * 32 + rr;
      const float bv = bias[o];
      v.x += bv; v.y += bv; v.z += bv; v.w += bv;
      const int p = p0 + c4 * 4;
      const int bidx = p / HWN;               // 3136 % 4 == 0 -> no b straddle
      const int hw = p - bidx * HWN;
      *(float4*)(out + (size_t)bidx * ON * HWN + (size_t)o * HWN + hw) = v;
    }
  }
#undef PH00
#undef PH01
#undef PH11
#undef PH10
#undef MFMA16
#undef LOAD_A
#undef LOAD_B
#undef STAGE_A
#undef STAGE_B
}

extern "C" void kernel_launch(void* const* d_in, const int* in_sizes, int n_in,
                              void* d_out, int out_size, void* d_ws, size_t ws_size,
                              hipStream_t stream) {
  const float* x = (const float*)d_in[0];       // [16,128,56,56]
  const float* w_off = (const float*)d_in[1];   // [18,128]
  const float* b_off = (const float*)d_in[2];   // [18]
  const float* w_conv = (const float*)d_in[3];  // [512,1152]
  const float* b_conv = (const float*)d_in[4];  // [512]
  float* out = (float*)d_out;                   // [16,512,56,56] fp32

  // workspace layout (16B aligned):
  //   xt  : bf16 [B,HW,C]      12,845,056 B @ 0
  //   S   : bf16 [M,K]        115,605,504 B @ 12,845,056
  //   Wb  : bf16 [512,1152]     1,179,648 B @ 128,450,560
  //   ixy : float2 [M,F]        3,612,672 B @ 129,630,208   (total ~133.2 MB)
  char* ws = (char*)d_ws;
  unsigned short* xt = (unsigned short*)(ws);
  unsigned short* S = (unsigned short*)(ws + 12845056);
  unsigned short* Wb = (unsigned short*)(ws + 128450560);
  float2* ixy = (float2*)(ws + 129630208);

  k_transpose<<<dim3(98, 4, 16), 256, 0, stream>>>(x, xt);
  k_wconv<<<dim3(576), 256, 0, stream>>>((const float4*)w_conv, (ushort4*)Wb);
  k_offsets<<<dim3(196), 256, 0, stream>>>(xt, w_off, b_off, ixy);
  k_sample<<<dim3(14112), 256, 0, stream>>>(xt, ixy, S);
  k_gemm<<<dim3(392), 512, 0, stream>>>(Wb, S, b_conv, out);
}